// Round 14
// baseline (2066.431 us; speedup 1.0000x reference)
//
#include <hip/hip_runtime.h>
#include <math.h>

// LSTM persistent kernel, R14: dual-pipe k-split. One block per batch
// (64 blocks), 512 threads = 8 waves; wave wv owns all 4 gates of elements
// 16wv..16wv+15; one barrier/step; bias seeded in accumulators.
//
// R12/R13 post-mortem: wall = MFMA phase (520-620 cy) + VALU tail (~400 cy)
// SERIALIZED -- the per-step barrier phase-locks the 2 waves/SIMD, so the
// pipes never overlap. R14 splits K between the pipes inside each wave:
//   MFMA: k in [0,96)  -> 12 MFMAs/wave (pipe ~465 cy/SIMD)
//   fdot2: k in [96,128) of each lane's OWN tail row (128q+el) -> 16 dots,
//          issued BEFORE the MFMA waitcnt => VALU runs under in-flight MFMAs.
// R13's column-parallel tail (lane = gate q of element el) makes the 64
// lanes' tail rows exactly the 64 rows the wave owns -- a clean k-split.
constexpr int Hdim = 128;
constexpr int TMAX = 4096;

typedef _Float16 v8h __attribute__((ext_vector_type(8)));
typedef _Float16 v2h __attribute__((ext_vector_type(2)));
typedef float v4f __attribute__((ext_vector_type(4)));

template <int CTRL>
__device__ __forceinline__ float dppf(float v) {
  return __int_as_float(
      __builtin_amdgcn_update_dpp(0, __float_as_int(v), CTRL, 0xF, 0xF, true));
}

#if __has_builtin(__builtin_amdgcn_exp2f)
__device__ __forceinline__ float exp2_fast(float x) {
  return __builtin_amdgcn_exp2f(x);
}
#else
__device__ __forceinline__ float exp2_fast(float x) {
  return __expf(x * 0.6931471805599453f);
}
#endif

__device__ __forceinline__ float sel4(v4f d, int r) {
  const float s01 = (r & 1) ? d.y : d.x;
  const float s23 = (r & 1) ? d.w : d.z;
  return (r & 2) ? s23 : s01;
}

__global__ __launch_bounds__(512) void lstm_mfma(
    const float* __restrict__ data, const float* __restrict__ h0,
    const float* __restrict__ c0, const float* __restrict__ W_ih,
    const float* __restrict__ W_hh, const float* __restrict__ b_ih,
    const float* __restrict__ b_hh, const float* __restrict__ W_out,
    const float* __restrict__ b_out, float* __restrict__ out, int T) {
  __shared__ __align__(16) float xs[TMAX];
  __shared__ __align__(16) _Float16 hbuf[2][Hdim];

  const int b = blockIdx.x;
  const int tid = threadIdx.x;
  const int lane = tid & 63;
  const int wv = tid >> 6;  // wave 0..7 owns elements 16wv..16wv+15
  const int p = lane >> 4;  // 0..3 (row-quad within tile)
  const int m = lane & 15;  // column id (all D cols identical)
  const int q = m & 3;      // MY gate (0=i,1=f,2=g,3=o)
  const int s = m >> 2;     // MY element sub-index within the row-quad
  const int el = 16 * wv + 4 * p + s;  // my element

  // Stage input row (coalesced float4).
  {
    const float4* src = (const float4*)(data + (size_t)b * T);
    float4* dst = (float4*)xs;
    for (int i = tid; i < T / 4; i += 512) dst[i] = src[i];
  }

  constexpr float L2E = 1.44269504088896f;

  // A-frags, k-chunks 0..2 only (k<96): gate g -> rows [128g+16wv, +16),
  // lane holds A[m][32c+8p+j], pre-scaled by Mk(g). (May park in AGPRs --
  // free, MFMA sources AGPRs natively.)
  v8h a[4][3];
#pragma unroll
  for (int g = 0; g < 4; ++g) {
    const int row = 128 * g + 16 * wv + m;
    const float Mr = (g == 2) ? 2.0f * L2E : -L2E;
    const float* wr = W_hh + (size_t)row * Hdim + 8 * p;
#pragma unroll
    for (int c = 0; c < 3; ++c) {
      float4 v0 = ((const float4*)(wr + 32 * c))[0];
      float4 v1 = ((const float4*)(wr + 32 * c))[1];
      a[g][c] = v8h{(_Float16)(Mr * v0.x), (_Float16)(Mr * v0.y),
                    (_Float16)(Mr * v0.z), (_Float16)(Mr * v0.w),
                    (_Float16)(Mr * v1.x), (_Float16)(Mr * v1.y),
                    (_Float16)(Mr * v1.z), (_Float16)(Mr * v1.w)};
    }
  }

  // fdot2 weights for MY tail row (128q+el), k in [96,128), Mk-scaled.
  const int rowt = 128 * q + el;
  const float Mt = (q == 2) ? 2.0f * L2E : -L2E;
  v2h wt[16];
  {
    const float* wrt = W_hh + (size_t)rowt * Hdim + 96;
#pragma unroll
    for (int j = 0; j < 16; ++j)
      wt[j] = v2h{(_Float16)(Mt * wrt[2 * j]), (_Float16)(Mt * wrt[2 * j + 1])};
  }

  // Accumulator seeds: acc_init[g].reg = Mk(g)*(b_ih+b_hh) of row
  // 128g + 16wv + 4p + reg (valid for every col m -> all lanes).
  v4f acc_init[4];
#pragma unroll
  for (int g = 0; g < 4; ++g) {
    const float Mr = (g == 2) ? 2.0f * L2E : -L2E;
    const int row = 128 * g + 16 * wv + 4 * p;
    acc_init[g] = v4f{Mr * (b_ih[row + 0] + b_hh[row + 0]),
                      Mr * (b_ih[row + 1] + b_hh[row + 1]),
                      Mr * (b_ih[row + 2] + b_hh[row + 2]),
                      Mr * (b_ih[row + 3] + b_hh[row + 3])};
  }

  // Per-lane tail constants for MY (gate q, element el).
  const float wihL = Mt * W_ih[rowt];
  const float As = (q == 2) ? -2.0f : 1.0f;
  const float Bs = (q == 2) ? 1.0f : 0.0f;

  float cst = c0[(size_t)b * Hdim + el];  // quad-redundant copy
  if (tid < 128) hbuf[0][tid] = (_Float16)h0[(size_t)b * Hdim + tid];
  __syncthreads();

  for (int t0 = 0; t0 < T; t0 += 4) {
    const float4 xv = *(const float4*)&xs[t0];  // 4 steps of x, one read
    const float xts[4] = {xv.x, xv.y, xv.z, xv.w};
#pragma unroll
    for (int u = 0; u < 4; ++u) {
      const int t = t0 + u;
      const _Float16* hb = hbuf[t & 1];
      // B-frags for MFMA chunks 0..2: lane reads h[32c+8p+j] (broadcast).
      v8h bq[3];
#pragma unroll
      for (int c = 0; c < 3; ++c) bq[c] = *(const v8h*)(hb + 32 * c + 8 * p);
      // Tail-chunk h (k 96..127), lane-uniform broadcast: 2x v8h.
      const v8h ht0 = *(const v8h*)(hb + 96);
      const v8h ht1 = *(const v8h*)(hb + 104);
      const v8h ht2 = *(const v8h*)(hb + 112);
      const v8h ht3 = *(const v8h*)(hb + 120);
      const float xt = xts[u];

      // MFMA: 4 independent gate chains x 3 chunks, c-major, bias-seeded.
      v4f d0 = acc_init[0], d1 = acc_init[1], d2 = acc_init[2],
          d3 = acc_init[3];
#pragma unroll
      for (int c = 0; c < 3; ++c) {
        d0 = __builtin_amdgcn_mfma_f32_16x16x32_f16(a[0][c], bq[c], d0, 0, 0, 0);
        d1 = __builtin_amdgcn_mfma_f32_16x16x32_f16(a[1][c], bq[c], d1, 0, 0, 0);
        d2 = __builtin_amdgcn_mfma_f32_16x16x32_f16(a[2][c], bq[c], d2, 0, 0, 0);
        d3 = __builtin_amdgcn_mfma_f32_16x16x32_f16(a[3][c], bq[c], d3, 0, 0, 0);
      }

      // fdot2 on MY tail row, k 96..127 -- independent of the MFMAs above:
      // issues on the VALU while the matrix pipe drains.
      float zt = 0.f;
#pragma unroll
      for (int j = 0; j < 4; ++j)
        zt = __builtin_amdgcn_fdot2(
            wt[j], v2h{ht0[2 * j], ht0[2 * j + 1]}, zt, false);
#pragma unroll
      for (int j = 0; j < 4; ++j)
        zt = __builtin_amdgcn_fdot2(
            wt[4 + j], v2h{ht1[2 * j], ht1[2 * j + 1]}, zt, false);
#pragma unroll
      for (int j = 0; j < 4; ++j)
        zt = __builtin_amdgcn_fdot2(
            wt[8 + j], v2h{ht2[2 * j], ht2[2 * j + 1]}, zt, false);
#pragma unroll
      for (int j = 0; j < 4; ++j)
        zt = __builtin_amdgcn_fdot2(
            wt[12 + j], v2h{ht3[2 * j], ht3[2 * j + 1]}, zt, false);

      // Column-parallel tail: select MY gate's MFMA partial, add fdot part.
      const float z0 = sel4(d0, s);
      const float z1 = sel4(d1, s);
      const float z2 = sel4(d2, s);
      const float z3 = sel4(d3, s);
      const float zq = (q & 2) ? ((q & 1) ? z3 : z2) : ((q & 1) ? z1 : z0);

      const float y = fmaf(
          As, __builtin_amdgcn_rcpf(1.0f + exp2_fast(fmaf(xt, wihL, zq + zt))),
          Bs);

      // Quad holds i,f,g,o of MY element -> DPP broadcast (R5-verified).
      const float yi = dppf<0x00>(y);
      const float yf = dppf<0x55>(y);
      const float yg = dppf<0xAA>(y);
      const float yo = dppf<0xFF>(y);

      cst = fmaf(yf, cst, yi * yg);
      const float th = fmaf(
          -2.0f, __builtin_amdgcn_rcpf(1.0f + exp2_fast(cst * (2.0f * L2E))),
          1.0f);
      const float h = yo * th;

      if (q == 0) hbuf[(t + 1) & 1][el] = (_Float16)h;
      __syncthreads();
    }
  }

  // Final linear: out[b] = h_T . W_out + b_out (wave 0).
  if (tid < 64) {
    const _Float16* hf = hbuf[T & 1];
    float sum =
        (float)hf[tid] * W_out[tid] + (float)hf[tid + 64] * W_out[tid + 64];
#pragma unroll
    for (int off = 32; off > 0; off >>= 1) sum += __shfl_down(sum, off, 64);
    if (tid == 0) out[b] = sum + b_out[0];
  }
}

extern "C" void kernel_launch(void* const* d_in, const int* in_sizes, int n_in,
                              void* d_out, int out_size, void* d_ws,
                              size_t ws_size, hipStream_t stream) {
  const float* data = (const float*)d_in[0];
  const float* h0 = (const float*)d_in[1];
  const float* c0 = (const float*)d_in[2];
  const float* W_ih = (const float*)d_in[3];
  const float* W_hh = (const float*)d_in[4];
  const float* b_ih = (const float*)d_in[5];
  const float* b_hh = (const float*)d_in[6];
  const float* W_out = (const float*)d_in[7];
  const float* b_out = (const float*)d_in[8];
  float* out = (float*)d_out;

  const int B = in_sizes[1] / Hdim;  // 64
  const int T = in_sizes[0] / B;     // 4096

  lstm_mfma<<<B, 512, 0, stream>>>(data, h0, c0, W_ih, W_hh, b_ih, b_hh,
                                   W_out, b_out, out, T);
}

// Round 15
// 1681.098 us; speedup vs baseline: 1.2292x; 1.2292x over previous
//
#include <hip/hip_runtime.h>
#include <math.h>

// LSTM persistent kernel, R15: R12 (best verified: 1684us) with the
// accumulator-copy tax removed. One block per batch (64 blocks), 512
// threads = 8 waves; wave wv owns all 4 gates of elements 16wv..16wv+15;
// in-wave tail (all 4 gate chains per lane); one barrier/step.
//
// R12-R14 consolidated model: wall = MFMA-pipe busy (525cy) + VALU busy
// (525cy) + bubbles, phase-locked by the barrier -- shifting work between
// pipes (R11/R14) is zero-sum; only REMOVING cycles helps. R15 removes the
// 16 accvgpr copies/wave/step of R12's "d = acc_init" seeding by sourcing
// the bias directly as the C operand of the FIRST MFMA in each chain
// (bit-identical fp32 semantics, -64 cy/SIMD/step).
constexpr int Hdim = 128;
constexpr int TMAX = 4096;

typedef _Float16 v8h __attribute__((ext_vector_type(8)));
typedef float v4f __attribute__((ext_vector_type(4)));

#if __has_builtin(__builtin_amdgcn_exp2f)
__device__ __forceinline__ float exp2_fast(float x) {
  return __builtin_amdgcn_exp2f(x);
}
#else
__device__ __forceinline__ float exp2_fast(float x) {
  return __expf(x * 0.6931471805599453f);
}
#endif

__device__ __forceinline__ float sel4(v4f d, int r) {
  const float s01 = (r & 1) ? d.y : d.x;
  const float s23 = (r & 1) ? d.w : d.z;
  return (r & 2) ? s23 : s01;
}

__global__ __launch_bounds__(512) void lstm_mfma(
    const float* __restrict__ data, const float* __restrict__ h0,
    const float* __restrict__ c0, const float* __restrict__ W_ih,
    const float* __restrict__ W_hh, const float* __restrict__ b_ih,
    const float* __restrict__ b_hh, const float* __restrict__ W_out,
    const float* __restrict__ b_out, float* __restrict__ out, int T) {
  __shared__ __align__(16) float xs[TMAX];
  __shared__ __align__(16) _Float16 hbuf[2][Hdim];

  const int b = blockIdx.x;
  const int tid = threadIdx.x;
  const int lane = tid & 63;
  const int wv = tid >> 6;  // wave 0..7 owns elements 16wv..16wv+15
  const int p = lane >> 4;  // 0..3
  const int m = lane & 15;  // column id (all D cols identical)
  const int r = m & 3;      // which d-component this lane's tail handles
  const int el = 16 * wv + 4 * p + r;  // my tail element

  // Stage input row (coalesced float4).
  {
    const float4* src = (const float4*)(data + (size_t)b * T);
    float4* dst = (float4*)xs;
    for (int i = tid; i < T / 4; i += 512) dst[i] = src[i];
  }

  constexpr float L2E = 1.44269504088896f;

  // A-frags: gate g -> rows [128g+16wv, 128g+16wv+16), chunk c -> k in
  // [32c,32c+32). Lane holds A[m][32c+8p+j], j=0..7, pre-scaled by Mk(g).
  v8h a[4][4];
#pragma unroll
  for (int g = 0; g < 4; ++g) {
    const int row = 128 * g + 16 * wv + m;
    const float Mr = (g == 2) ? 2.0f * L2E : -L2E;
    const float* wr = W_hh + (size_t)row * Hdim + 8 * p;
#pragma unroll
    for (int c = 0; c < 4; ++c) {
      float4 v0 = ((const float4*)(wr + 32 * c))[0];
      float4 v1 = ((const float4*)(wr + 32 * c))[1];
      a[g][c] = v8h{(_Float16)(Mr * v0.x), (_Float16)(Mr * v0.y),
                    (_Float16)(Mr * v0.z), (_Float16)(Mr * v0.w),
                    (_Float16)(Mr * v1.x), (_Float16)(Mr * v1.y),
                    (_Float16)(Mr * v1.z), (_Float16)(Mr * v1.w)};
    }
  }

  // Bias seeds: acc_init[g].reg = Mk(g)*(b_ih+b_hh) of row 128g+16wv+4p+reg.
  // Used directly as the C operand of the FIRST MFMA of each chain.
  v4f acc_init[4];
#pragma unroll
  for (int g = 0; g < 4; ++g) {
    const float Mr = (g == 2) ? 2.0f * L2E : -L2E;
    const int row = 128 * g + 16 * wv + 4 * p;
    acc_init[g] = v4f{Mr * (b_ih[row + 0] + b_hh[row + 0]),
                      Mr * (b_ih[row + 1] + b_hh[row + 1]),
                      Mr * (b_ih[row + 2] + b_hh[row + 2]),
                      Mr * (b_ih[row + 3] + b_hh[row + 3])};
  }

  // Tail constants: Mk-scaled W_ih for my element, per gate.
  float wih[4];
#pragma unroll
  for (int g = 0; g < 4; ++g) {
    const float Mr = (g == 2) ? 2.0f * L2E : -L2E;
    wih[g] = Mr * W_ih[128 * g + el];
  }

  float cst = c0[(size_t)b * Hdim + el];
  if (tid < 128) hbuf[0][tid] = (_Float16)h0[(size_t)b * Hdim + tid];
  __syncthreads();

  for (int t0 = 0; t0 < T; t0 += 4) {
    const float4 xv = *(const float4*)&xs[t0];  // 4 steps of x, one read
    const float xts[4] = {xv.x, xv.y, xv.z, xv.w};
#pragma unroll
    for (int u = 0; u < 4; ++u) {
      const int t = t0 + u;
      const _Float16* hb = hbuf[t & 1];
      _Float16* hn = hbuf[(t + 1) & 1];
      // B-frags: h chunk c, lane reads h[32c+8p+j] (16-lane broadcast).
      v8h bq[4];
#pragma unroll
      for (int c = 0; c < 4; ++c) bq[c] = *(const v8h*)(hb + 32 * c + 8 * p);
      const float xt = xts[u];

      // 4 independent gate chains, c-major; chunk 0 sources the bias as C
      // directly (no accumulator-init copies).
      v4f d0 = __builtin_amdgcn_mfma_f32_16x16x32_f16(a[0][0], bq[0],
                                                      acc_init[0], 0, 0, 0);
      v4f d1 = __builtin_amdgcn_mfma_f32_16x16x32_f16(a[1][0], bq[0],
                                                      acc_init[1], 0, 0, 0);
      v4f d2 = __builtin_amdgcn_mfma_f32_16x16x32_f16(a[2][0], bq[0],
                                                      acc_init[2], 0, 0, 0);
      v4f d3 = __builtin_amdgcn_mfma_f32_16x16x32_f16(a[3][0], bq[0],
                                                      acc_init[3], 0, 0, 0);
#pragma unroll
      for (int c = 1; c < 4; ++c) {
        d0 = __builtin_amdgcn_mfma_f32_16x16x32_f16(a[0][c], bq[c], d0, 0, 0, 0);
        d1 = __builtin_amdgcn_mfma_f32_16x16x32_f16(a[1][c], bq[c], d1, 0, 0, 0);
        d2 = __builtin_amdgcn_mfma_f32_16x16x32_f16(a[2][c], bq[c], d2, 0, 0, 0);
        d3 = __builtin_amdgcn_mfma_f32_16x16x32_f16(a[3][c], bq[c], d3, 0, 0, 0);
      }

      // In-wave tail: my element's 4 gate preacts (bias already inside).
      const float zi = sel4(d0, r);
      const float zf = sel4(d1, r);
      const float zg = sel4(d2, r);
      const float zo = sel4(d3, r);

      const float yi =
          __builtin_amdgcn_rcpf(1.0f + exp2_fast(fmaf(xt, wih[0], zi)));
      const float yf =
          __builtin_amdgcn_rcpf(1.0f + exp2_fast(fmaf(xt, wih[1], zf)));
      const float yg = fmaf(
          -2.0f, __builtin_amdgcn_rcpf(1.0f + exp2_fast(fmaf(xt, wih[2], zg))),
          1.0f);
      const float yo =
          __builtin_amdgcn_rcpf(1.0f + exp2_fast(fmaf(xt, wih[3], zo)));

      cst = fmaf(yf, cst, yi * yg);
      const float th = fmaf(
          -2.0f, __builtin_amdgcn_rcpf(1.0f + exp2_fast(cst * (2.0f * L2E))),
          1.0f);
      const float h = yo * th;

      if (m < 4) hn[el] = (_Float16)h;
      __syncthreads();
    }
  }

  // Final linear: out[b] = h_T . W_out + b_out (wave 0).
  if (tid < 64) {
    const _Float16* hf = hbuf[T & 1];
    float sum =
        (float)hf[tid] * W_out[tid] + (float)hf[tid + 64] * W_out[tid + 64];
#pragma unroll
    for (int off = 32; off > 0; off >>= 1) sum += __shfl_down(sum, off, 64);
    if (tid == 0) out[b] = sum + b_out[0];
  }
}

extern "C" void kernel_launch(void* const* d_in, const int* in_sizes, int n_in,
                              void* d_out, int out_size, void* d_ws,
                              size_t ws_size, hipStream_t stream) {
  const float* data = (const float*)d_in[0];
  const float* h0 = (const float*)d_in[1];
  const float* c0 = (const float*)d_in[2];
  const float* W_ih = (const float*)d_in[3];
  const float* W_hh = (const float*)d_in[4];
  const float* b_ih = (const float*)d_in[5];
  const float* b_hh = (const float*)d_in[6];
  const float* W_out = (const float*)d_in[7];
  const float* b_out = (const float*)d_in[8];
  float* out = (float*)d_out;

  const int B = in_sizes[1] / Hdim;  // 64
  const int T = in_sizes[0] / B;     // 4096

  lstm_mfma<<<B, 512, 0, stream>>>(data, h0, c0, W_ih, W_hh, b_ih, b_hh,
                                   W_out, b_out, out, T);
}